// Round 7
// baseline (270.679 us; speedup 1.0000x reference)
//
#include <hip/hip_runtime.h>
#include <math.h>

#define DIM 64
#define FDIM 256   // DIM * H (H=4)
#define DEFER_THR 4.0f

// bf16 (stored as ushort) -> float helpers: elem pair packed in a uint
__device__ __forceinline__ float blo(unsigned int u) {
    union { unsigned int i; float f; } x; x.i = u << 16; return x.f;
}
__device__ __forceinline__ float bhi(unsigned int u) {
    union { unsigned int i; float f; } x; x.i = u & 0xffff0000u; return x.f;
}
__device__ __forceinline__ void cvt16(uint4 a, uint4 b, float* f) {
    f[0]=blo(a.x);  f[1]=bhi(a.x);  f[2]=blo(a.y);  f[3]=bhi(a.y);
    f[4]=blo(a.z);  f[5]=bhi(a.z);  f[6]=blo(a.w);  f[7]=bhi(a.w);
    f[8]=blo(b.x);  f[9]=bhi(b.x);  f[10]=blo(b.y); f[11]=bhi(b.y);
    f[12]=blo(b.z); f[13]=bhi(b.z); f[14]=blo(b.w); f[15]=bhi(b.w);
}

// ---------------- zero cnt ----------------
__global__ void zero_kernel(int* __restrict__ p, int n)
{
    int i = blockIdx.x * blockDim.x + threadIdx.x;
    for (; i < n; i += gridDim.x * blockDim.x) p[i] = 0;
}

// ---------------- Fused: fc (blocks [0,fcB)) + hist (blocks [fcB, grid)) ----------------
// fc: ft = bf16(h_v @ W_fc^T + b_fc); thread t owns output column t, h row is wave-uniform.
// hist: cnt[dst[e]]++ over edges.
__global__ __launch_bounds__(256) void fc_hist_kernel(const float* __restrict__ h,
                                                      const float* __restrict__ W,
                                                      const float* __restrict__ b,
                                                      unsigned short* __restrict__ ft,
                                                      const int* __restrict__ dst,
                                                      int* __restrict__ cnt,
                                                      int N, int E, int fcB)
{
    if (blockIdx.x < fcB) {
        int t = threadIdx.x;              // output column 0..255
        float w[DIM];
#pragma unroll
        for (int j = 0; j < DIM / 4; ++j) {
            float4 v = *(const float4*)(W + (size_t)t * DIM + j * 4);
            w[4 * j + 0] = v.x; w[4 * j + 1] = v.y;
            w[4 * j + 2] = v.z; w[4 * j + 3] = v.w;
        }
        float bt = b[t];
        for (int r = blockIdx.x; r < N; r += fcB) {
            const float4* h4 = (const float4*)(h + (size_t)r * DIM);
            float acc = bt;
#pragma unroll
            for (int j = 0; j < DIM / 4; ++j) {
                float4 hv = h4[j];       // uniform address across the wave
                acc = fmaf(hv.x, w[4 * j + 0], acc);
                acc = fmaf(hv.y, w[4 * j + 1], acc);
                acc = fmaf(hv.z, w[4 * j + 2], acc);
                acc = fmaf(hv.w, w[4 * j + 3], acc);
            }
            union { float f; unsigned int i; } x; x.f = acc;     // RNE to bf16
            unsigned int r16 = (x.i + 0x7fffu + ((x.i >> 16) & 1u)) >> 16;
            ft[(size_t)r * FDIM + t] = (unsigned short)r16;
        }
    } else {
        int stride = (gridDim.x - fcB) * 256;
        int i = (blockIdx.x - fcB) * 256 + threadIdx.x;
        for (; i < E; i += stride) atomicAdd(&cnt[dst[i]], 1);
    }
}

// ---------------- Multi-block exclusive scan of cnt[0..N) ----------------
__global__ __launch_bounds__(256) void scanA_kernel(const int* __restrict__ cnt,
                                                    int* __restrict__ off,
                                                    int* __restrict__ bsum, int N)
{
    __shared__ int sh[256];
    int t = threadIdx.x;
    int i = blockIdx.x * 256 + t;
    int v = (i < N) ? cnt[i] : 0;
    sh[t] = v;
    __syncthreads();
#pragma unroll
    for (int o = 1; o < 256; o <<= 1) {
        int x = (t >= o) ? sh[t - o] : 0;
        __syncthreads();
        sh[t] += x;
        __syncthreads();
    }
    if (i < N) off[i] = sh[t] - v;          // local exclusive
    if (t == 255) bsum[blockIdx.x] = sh[255];
}

__global__ __launch_bounds__(256) void scanB_kernel(int* __restrict__ bsum, int nb)
{
    __shared__ int sh[256];
    int t = threadIdx.x;
    int carry = 0;
    for (int base = 0; base < nb; base += 256) {
        int i = base + t;
        int v = (i < nb) ? bsum[i] : 0;
        sh[t] = v;
        __syncthreads();
#pragma unroll
        for (int o = 1; o < 256; o <<= 1) {
            int x = (t >= o) ? sh[t - o] : 0;
            __syncthreads();
            sh[t] += x;
            __syncthreads();
        }
        if (i < nb) bsum[i] = carry + sh[t] - v;   // exclusive
        int tot = sh[255];
        __syncthreads();
        carry += tot;
    }
}

__global__ void scanC_kernel(int* __restrict__ off, int* __restrict__ cur,
                             const int* __restrict__ bsum, int N, int E)
{
    int i = blockIdx.x * blockDim.x + threadIdx.x;
    if (i < N) {
        int v = off[i] + bsum[i >> 8];
        off[i] = v;
        cur[i] = v;
    }
    if (i == 0) off[N] = E;
}

__global__ void scatter_kernel(const int* __restrict__ src, const int* __restrict__ dst,
                               int* __restrict__ cur, int* __restrict__ ssrc, int E)
{
    int i = blockIdx.x * blockDim.x + threadIdx.x;
    for (; i < E; i += gridDim.x * blockDim.x) {
        int d = dst[i];
        int pos = atomicAdd(&cur[d], 1);
        ssrc[pos] = src[i];
    }
}

// ---------------- Fused: score + edge-softmax + weighted sum + head-max ----------------
// Persistent waves; one wave per node at a time, 4 edges/iter, software-pipelined 1 ahead.
// Quarter q (16 lanes) owns edge base+q with its OWN online softmax (m_q,l_q,acc_q);
// states merged at the epilogue. Lane ql owns dims 16*ql..16*ql+15.
__global__ __launch_bounds__(256) void agg_kernel(const unsigned short* __restrict__ ft,
                                                  const int* __restrict__ off,
                                                  const int* __restrict__ ssrc,
                                                  const float* __restrict__ Wpi,
                                                  float* __restrict__ out, int N)
{
    int nwaves = gridDim.x * (blockDim.x >> 6);
    int gw = blockIdx.x * (blockDim.x >> 6) + (threadIdx.x >> 6);
    int lane = threadIdx.x & 63;
    int q  = lane >> 4;
    int ql = lane & 15;

    // Wpi slice for this lane's 16 dims (node-independent, hoisted)
    float wq[16];
    {
        const float4* wp4 = (const float4*)(Wpi + ql * 16);
#pragma unroll
        for (int j = 0; j < 4; ++j) {
            float4 w = wp4[j];
            wq[4 * j + 0] = w.x; wq[4 * j + 1] = w.y;
            wq[4 * j + 2] = w.z; wq[4 * j + 3] = w.w;
        }
    }

    for (int wid = gw; wid < N; wid += nwaves) {
        // fdw[j] = ft[wid][16*ql+j] * Wpi[16*ql+j]
        float fdw[16];
        {
            const unsigned short* drow = ft + (size_t)wid * FDIM + ql * 16;
            uint4 a = *(const uint4*)(drow);
            uint4 b = *(const uint4*)(drow + 8);
            float fd[16];
            cvt16(a, b, fd);
#pragma unroll
            for (int j = 0; j < 16; ++j) fdw[j] = fd[j] * wq[j];
        }

        int e0 = off[wid], e1 = off[wid + 1];
        float mq = -INFINITY, lq = 0.f;
        float acc[16];
#pragma unroll
        for (int j = 0; j < 16; ++j) acc[j] = 0.f;

        auto LOAD = [&](uint4& ra, uint4& rb, bool& val, int bse) {
            int ei = bse + q;
            val = ei < e1;
            int sv = ssrc[val ? ei : bse];
            const unsigned short* srow = ft + (size_t)sv * FDIM + ql * 16;
            ra = *(const uint4*)(srow);
            rb = *(const uint4*)(srow + 8);
        };
        auto COMP = [&](uint4 ra, uint4 rb, bool val) {
            float fs[16];
            cvt16(ra, rb, fs);
            float p = 0.f;
#pragma unroll
            for (int j = 0; j < 16; ++j) p = fmaf(fs[j], fdw[j], p);
            p += __shfl_xor(p, 1, 64);
            p += __shfl_xor(p, 2, 64);
            p += __shfl_xor(p, 4, 64);
            p += __shfl_xor(p, 8, 64);
            float s = p > 0.f ? p : 0.2f * p;       // LeakyReLU(0.2)
            if (val) {                               // quarter-divergent
                if (s > mq + DEFER_THR) {            // T13 defer-max; first edge: -inf -> taken
                    float sc = __expf(mq - s);       // first: exp(-inf)=0
                    lq *= sc;
#pragma unroll
                    for (int j = 0; j < 16; ++j) acc[j] *= sc;
                    mq = s;
                }
                float pe = __expf(s - mq);           // bounded by e^THR
                lq += pe;
#pragma unroll
                for (int j = 0; j < 16; ++j) acc[j] = fmaf(pe, fs[j], acc[j]);
            }
        };

        if (e0 < e1) {
            uint4 Aa, Ab, Ba, Bb;
            bool Av = false, Bv = false;
            int base = e0;
            LOAD(Aa, Ab, Av, base);
            while (true) {
                int nxt = base + 4;
                if (nxt < e1) LOAD(Ba, Bb, Bv, nxt);
                COMP(Aa, Ab, Av);
                base = nxt;
                if (base >= e1) break;
                nxt = base + 4;
                if (nxt < e1) LOAD(Aa, Ab, Av, nxt);
                COMP(Ba, Bb, Bv);
                base = nxt;
                if (base >= e1) break;
            }
        }

        // merge 4 quarter softmax states
        float mstar = fmaxf(mq, __shfl_xor(mq, 16, 64));
        mstar = fmaxf(mstar, __shfl_xor(mstar, 32, 64));
        float sc = (lq > 0.f) ? __expf(mq - mstar) : 0.f;
        float lt = lq * sc;
        lt += __shfl_xor(lt, 16, 64);
        lt += __shfl_xor(lt, 32, 64);
        float inv = (lt > 0.f) ? 1.f / lt : 0.f;

        // quarter-sum, head-max (head = ql>>2 -> xor lane bits 2,3), normalize
        float r[16];
#pragma unroll
        for (int j = 0; j < 16; ++j) {
            float v = acc[j] * sc;
            v += __shfl_xor(v, 16, 64);
            v += __shfl_xor(v, 32, 64);
            v = fmaxf(v, __shfl_xor(v, 4, 64));
            v = fmaxf(v, __shfl_xor(v, 8, 64));
            r[j] = v * inv;
        }
        if (lane < 4) {                              // q==0, ql 0..3: dims 16*ql..16*ql+15
            float4* o4 = (float4*)(out + (size_t)wid * DIM + ql * 16);
            o4[0] = make_float4(r[0],  r[1],  r[2],  r[3]);
            o4[1] = make_float4(r[4],  r[5],  r[6],  r[7]);
            o4[2] = make_float4(r[8],  r[9],  r[10], r[11]);
            o4[3] = make_float4(r[12], r[13], r[14], r[15]);
        }
    }
}

extern "C" void kernel_launch(void* const* d_in, const int* in_sizes, int n_in,
                              void* d_out, int out_size, void* d_ws, size_t ws_size,
                              hipStream_t stream)
{
    const float* h_v  = (const float*)d_in[0];
    const int*   src  = (const int*)d_in[1];
    const int*   dst  = (const int*)d_in[2];
    const float* W_fc = (const float*)d_in[3];
    const float* b_fc = (const float*)d_in[4];
    const float* W_pi = (const float*)d_in[5];
    float* out = (float*)d_out;

    int N = in_sizes[0] / DIM;
    int E = in_sizes[1];

    // workspace layout
    unsigned short* ft = (unsigned short*)d_ws;            // N*256*2 = 25.6 MB
    size_t ftB = (((size_t)N * FDIM * 2) + 255) & ~(size_t)255;
    char*  p    = (char*)d_ws + ftB;
    int*   cnt  = (int*)(p);                               // N
    int*   off  = (int*)(p + 256 * 1024);                  // N+1
    int*   cur  = (int*)(p + 512 * 1024);                  // N
    int*   bsum = (int*)(p + 768 * 1024);                  // ceil(N/256)
    int*   ssrc = (int*)(p + 1024 * 1024);                 // E

    int nb = (N + 255) / 256;
    const int fcB = 1024, histB = 512;
    zero_kernel<<<256, 256, 0, stream>>>(cnt, N);
    fc_hist_kernel<<<fcB + histB, 256, 0, stream>>>(h_v, W_fc, b_fc, ft, dst, cnt, N, E, fcB);
    scanA_kernel<<<nb, 256, 0, stream>>>(cnt, off, bsum, N);
    scanB_kernel<<<1, 256, 0, stream>>>(bsum, nb);
    scanC_kernel<<<nb, 256, 0, stream>>>(off, cur, bsum, N, E);
    scatter_kernel<<<1024, 256, 0, stream>>>(src, dst, cur, ssrc, E);
    agg_kernel<<<2048, 256, 0, stream>>>(ft, off, ssrc, W_pi, out, N);
}

// Round 8
// 237.276 us; speedup vs baseline: 1.1408x; 1.1408x over previous
//
#include <hip/hip_runtime.h>
#include <math.h>

#define DIM 64
#define FDIM 256   // DIM * H (H=4)
#define DEFER_THR 4.0f

// bf16 (stored as ushort) -> float helpers: elem pair packed in a uint
__device__ __forceinline__ float blo(unsigned int u) {
    union { unsigned int i; float f; } x; x.i = u << 16; return x.f;
}
__device__ __forceinline__ float bhi(unsigned int u) {
    union { unsigned int i; float f; } x; x.i = u & 0xffff0000u; return x.f;
}
__device__ __forceinline__ void cvt16(uint4 a, uint4 b, float* f) {
    f[0]=blo(a.x);  f[1]=bhi(a.x);  f[2]=blo(a.y);  f[3]=bhi(a.y);
    f[4]=blo(a.z);  f[5]=bhi(a.z);  f[6]=blo(a.w);  f[7]=bhi(a.w);
    f[8]=blo(b.x);  f[9]=bhi(b.x);  f[10]=blo(b.y); f[11]=bhi(b.y);
    f[12]=blo(b.z); f[13]=bhi(b.z); f[14]=blo(b.w); f[15]=bhi(b.w);
}
__device__ __forceinline__ unsigned short f2bf(float f) {
    union { float f; unsigned int i; } x; x.f = f;
    return (unsigned short)((x.i + 0x7fffu + ((x.i >> 16) & 1u)) >> 16);
}

// ---------------- Stage 1: ft = bf16(h_v @ W_fc^T + b_fc)  -> [N, 256] ----------------
// Thread t owns output column t; 4 rows at a time -> 4 independent FMA chains (ILP),
// h-row values wave-uniform (L1 broadcast / scalar loads).
__global__ __launch_bounds__(256) void fc_kernel(const float* __restrict__ h,
                                                 const float* __restrict__ W,
                                                 const float* __restrict__ b,
                                                 unsigned short* __restrict__ ft, int N)
{
    int t = threadIdx.x;              // output column 0..255
    float w[DIM];
#pragma unroll
    for (int j = 0; j < DIM / 4; ++j) {
        float4 v = *(const float4*)(W + (size_t)t * DIM + j * 4);
        w[4 * j + 0] = v.x; w[4 * j + 1] = v.y;
        w[4 * j + 2] = v.z; w[4 * j + 3] = v.w;
    }
    float bt = b[t];
    int ng = N >> 2;                  // groups of 4 rows
    for (int g = blockIdx.x; g < ng; g += gridDim.x) {
        int r0 = g * 4;
        const float4* h4 = (const float4*)(h + (size_t)r0 * DIM);
        float a0 = bt, a1 = bt, a2 = bt, a3 = bt;
#pragma unroll
        for (int j = 0; j < DIM / 4; ++j) {
            float4 v0 = h4[j];
            float4 v1 = h4[16 + j];
            float4 v2 = h4[32 + j];
            float4 v3 = h4[48 + j];
            a0 = fmaf(v0.x, w[4*j+0], a0); a0 = fmaf(v0.y, w[4*j+1], a0);
            a0 = fmaf(v0.z, w[4*j+2], a0); a0 = fmaf(v0.w, w[4*j+3], a0);
            a1 = fmaf(v1.x, w[4*j+0], a1); a1 = fmaf(v1.y, w[4*j+1], a1);
            a1 = fmaf(v1.z, w[4*j+2], a1); a1 = fmaf(v1.w, w[4*j+3], a1);
            a2 = fmaf(v2.x, w[4*j+0], a2); a2 = fmaf(v2.y, w[4*j+1], a2);
            a2 = fmaf(v2.z, w[4*j+2], a2); a2 = fmaf(v2.w, w[4*j+3], a2);
            a3 = fmaf(v3.x, w[4*j+0], a3); a3 = fmaf(v3.y, w[4*j+1], a3);
            a3 = fmaf(v3.z, w[4*j+2], a3); a3 = fmaf(v3.w, w[4*j+3], a3);
        }
        unsigned short* o = ft + (size_t)r0 * FDIM + t;
        o[0]        = f2bf(a0);
        o[FDIM]     = f2bf(a1);
        o[2 * FDIM] = f2bf(a2);
        o[3 * FDIM] = f2bf(a3);
    }
    // tail rows (N % 4)
    for (int r = (ng << 2) + blockIdx.x; r < N; r += gridDim.x) {
        const float4* h4 = (const float4*)(h + (size_t)r * DIM);
        float acc = bt;
#pragma unroll
        for (int j = 0; j < DIM / 4; ++j) {
            float4 hv = h4[j];
            acc = fmaf(hv.x, w[4*j+0], acc); acc = fmaf(hv.y, w[4*j+1], acc);
            acc = fmaf(hv.z, w[4*j+2], acc); acc = fmaf(hv.w, w[4*j+3], acc);
        }
        ft[(size_t)r * FDIM + t] = f2bf(acc);
    }
}

// ---------------- Counting sort of edges by dst ----------------
__global__ void zero_kernel(int* __restrict__ p, int n)
{
    int i = blockIdx.x * blockDim.x + threadIdx.x;
    for (; i < n; i += gridDim.x * blockDim.x) p[i] = 0;
}

__global__ void hist_kernel(const int* __restrict__ dst, int* __restrict__ cnt, int E)
{
    int i = blockIdx.x * blockDim.x + threadIdx.x;
    for (; i < E; i += gridDim.x * blockDim.x) atomicAdd(&cnt[dst[i]], 1);
}

// ---------------- Multi-block exclusive scan of cnt[0..N) ----------------
__global__ __launch_bounds__(256) void scanA_kernel(const int* __restrict__ cnt,
                                                    int* __restrict__ off,
                                                    int* __restrict__ bsum, int N)
{
    __shared__ int sh[256];
    int t = threadIdx.x;
    int i = blockIdx.x * 256 + t;
    int v = (i < N) ? cnt[i] : 0;
    sh[t] = v;
    __syncthreads();
#pragma unroll
    for (int o = 1; o < 256; o <<= 1) {
        int x = (t >= o) ? sh[t - o] : 0;
        __syncthreads();
        sh[t] += x;
        __syncthreads();
    }
    if (i < N) off[i] = sh[t] - v;          // local exclusive
    if (t == 255) bsum[blockIdx.x] = sh[255];
}

__global__ __launch_bounds__(256) void scanB_kernel(int* __restrict__ bsum, int nb)
{
    __shared__ int sh[256];
    int t = threadIdx.x;
    int carry = 0;
    for (int base = 0; base < nb; base += 256) {
        int i = base + t;
        int v = (i < nb) ? bsum[i] : 0;
        sh[t] = v;
        __syncthreads();
#pragma unroll
        for (int o = 1; o < 256; o <<= 1) {
            int x = (t >= o) ? sh[t - o] : 0;
            __syncthreads();
            sh[t] += x;
            __syncthreads();
        }
        if (i < nb) bsum[i] = carry + sh[t] - v;   // exclusive
        int tot = sh[255];
        __syncthreads();
        carry += tot;
    }
}

__global__ void scanC_kernel(int* __restrict__ off, int* __restrict__ cur,
                             const int* __restrict__ bsum, int N, int E)
{
    int i = blockIdx.x * blockDim.x + threadIdx.x;
    if (i < N) {
        int v = off[i] + bsum[i >> 8];
        off[i] = v;
        cur[i] = v;
    }
    if (i == 0) off[N] = E;
}

__global__ void scatter_kernel(const int* __restrict__ src, const int* __restrict__ dst,
                               int* __restrict__ cur, int* __restrict__ ssrc, int E)
{
    int i = blockIdx.x * blockDim.x + threadIdx.x;
    for (; i < E; i += gridDim.x * blockDim.x) {
        int d = dst[i];
        int pos = atomicAdd(&cur[d], 1);
        ssrc[pos] = src[i];
    }
}

// ---------------- Fused: score + edge-softmax + weighted sum + head-max ----------------
// Persistent waves; one wave per node at a time, 4 edges/iter, software-pipelined 1 ahead.
// Quarter q (16 lanes) owns edge base+q with its OWN online softmax (m_q,l_q,acc_q);
// states merged at the epilogue. Lane ql owns dims 16*ql..16*ql+15.
__global__ __launch_bounds__(256) void agg_kernel(const unsigned short* __restrict__ ft,
                                                  const int* __restrict__ off,
                                                  const int* __restrict__ ssrc,
                                                  const float* __restrict__ Wpi,
                                                  float* __restrict__ out, int N)
{
    int nwaves = gridDim.x * (blockDim.x >> 6);
    int gw = blockIdx.x * (blockDim.x >> 6) + (threadIdx.x >> 6);
    int lane = threadIdx.x & 63;
    int q  = lane >> 4;
    int ql = lane & 15;

    // Wpi slice for this lane's 16 dims (node-independent, hoisted)
    float wq[16];
    {
        const float4* wp4 = (const float4*)(Wpi + ql * 16);
#pragma unroll
        for (int j = 0; j < 4; ++j) {
            float4 w = wp4[j];
            wq[4 * j + 0] = w.x; wq[4 * j + 1] = w.y;
            wq[4 * j + 2] = w.z; wq[4 * j + 3] = w.w;
        }
    }

    for (int wid = gw; wid < N; wid += nwaves) {
        // fdw[j] = ft[wid][16*ql+j] * Wpi[16*ql+j]
        float fdw[16];
        {
            const unsigned short* drow = ft + (size_t)wid * FDIM + ql * 16;
            uint4 a = *(const uint4*)(drow);
            uint4 b = *(const uint4*)(drow + 8);
            float fd[16];
            cvt16(a, b, fd);
#pragma unroll
            for (int j = 0; j < 16; ++j) fdw[j] = fd[j] * wq[j];
        }

        int e0 = off[wid], e1 = off[wid + 1];
        float mq = -INFINITY, lq = 0.f;
        float acc[16];
#pragma unroll
        for (int j = 0; j < 16; ++j) acc[j] = 0.f;

        auto LOAD = [&](uint4& ra, uint4& rb, bool& val, int bse) {
            int ei = bse + q;
            val = ei < e1;
            int sv = ssrc[val ? ei : bse];
            const unsigned short* srow = ft + (size_t)sv * FDIM + ql * 16;
            ra = *(const uint4*)(srow);
            rb = *(const uint4*)(srow + 8);
        };
        auto COMP = [&](uint4 ra, uint4 rb, bool val) {
            float fs[16];
            cvt16(ra, rb, fs);
            float p = 0.f;
#pragma unroll
            for (int j = 0; j < 16; ++j) p = fmaf(fs[j], fdw[j], p);
            p += __shfl_xor(p, 1, 64);
            p += __shfl_xor(p, 2, 64);
            p += __shfl_xor(p, 4, 64);
            p += __shfl_xor(p, 8, 64);
            float s = p > 0.f ? p : 0.2f * p;       // LeakyReLU(0.2)
            if (val) {                               // quarter-divergent
                if (s > mq + DEFER_THR) {            // T13 defer-max; first edge: -inf -> taken
                    float sc = __expf(mq - s);       // first: exp(-inf)=0
                    lq *= sc;
#pragma unroll
                    for (int j = 0; j < 16; ++j) acc[j] *= sc;
                    mq = s;
                }
                float pe = __expf(s - mq);           // bounded by e^THR
                lq += pe;
#pragma unroll
                for (int j = 0; j < 16; ++j) acc[j] = fmaf(pe, fs[j], acc[j]);
            }
        };

        if (e0 < e1) {
            uint4 Aa, Ab, Ba, Bb;
            bool Av = false, Bv = false;
            int base = e0;
            LOAD(Aa, Ab, Av, base);
            while (true) {
                int nxt = base + 4;
                if (nxt < e1) LOAD(Ba, Bb, Bv, nxt);
                COMP(Aa, Ab, Av);
                base = nxt;
                if (base >= e1) break;
                nxt = base + 4;
                if (nxt < e1) LOAD(Aa, Ab, Av, nxt);
                COMP(Ba, Bb, Bv);
                base = nxt;
                if (base >= e1) break;
            }
        }

        // merge 4 quarter softmax states
        float mstar = fmaxf(mq, __shfl_xor(mq, 16, 64));
        mstar = fmaxf(mstar, __shfl_xor(mstar, 32, 64));
        float sc = (lq > 0.f) ? __expf(mq - mstar) : 0.f;
        float lt = lq * sc;
        lt += __shfl_xor(lt, 16, 64);
        lt += __shfl_xor(lt, 32, 64);
        float inv = (lt > 0.f) ? 1.f / lt : 0.f;

        // quarter-sum, head-max (head = ql>>2 -> xor lane bits 2,3), normalize
        float r[16];
#pragma unroll
        for (int j = 0; j < 16; ++j) {
            float v = acc[j] * sc;
            v += __shfl_xor(v, 16, 64);
            v += __shfl_xor(v, 32, 64);
            v = fmaxf(v, __shfl_xor(v, 4, 64));
            v = fmaxf(v, __shfl_xor(v, 8, 64));
            r[j] = v * inv;
        }
        if (lane < 4) {                              // q==0, ql 0..3: dims 16*ql..16*ql+15
            float4* o4 = (float4*)(out + (size_t)wid * DIM + ql * 16);
            o4[0] = make_float4(r[0],  r[1],  r[2],  r[3]);
            o4[1] = make_float4(r[4],  r[5],  r[6],  r[7]);
            o4[2] = make_float4(r[8],  r[9],  r[10], r[11]);
            o4[3] = make_float4(r[12], r[13], r[14], r[15]);
        }
    }
}

extern "C" void kernel_launch(void* const* d_in, const int* in_sizes, int n_in,
                              void* d_out, int out_size, void* d_ws, size_t ws_size,
                              hipStream_t stream)
{
    const float* h_v  = (const float*)d_in[0];
    const int*   src  = (const int*)d_in[1];
    const int*   dst  = (const int*)d_in[2];
    const float* W_fc = (const float*)d_in[3];
    const float* b_fc = (const float*)d_in[4];
    const float* W_pi = (const float*)d_in[5];
    float* out = (float*)d_out;

    int N = in_sizes[0] / DIM;
    int E = in_sizes[1];

    // workspace layout
    unsigned short* ft = (unsigned short*)d_ws;            // N*256*2 = 25.6 MB
    size_t ftB = (((size_t)N * FDIM * 2) + 255) & ~(size_t)255;
    char*  p    = (char*)d_ws + ftB;
    int*   cnt  = (int*)(p);                               // N
    int*   off  = (int*)(p + 256 * 1024);                  // N+1
    int*   cur  = (int*)(p + 512 * 1024);                  // N
    int*   bsum = (int*)(p + 768 * 1024);                  // ceil(N/256)
    int*   ssrc = (int*)(p + 1024 * 1024);                 // E

    int nb = (N + 255) / 256;
    fc_kernel<<<1024, 256, 0, stream>>>(h_v, W_fc, b_fc, ft, N);
    zero_kernel<<<256, 256, 0, stream>>>(cnt, N);
    hist_kernel<<<2048, 256, 0, stream>>>(dst, cnt, E);
    scanA_kernel<<<nb, 256, 0, stream>>>(cnt, off, bsum, N);
    scanB_kernel<<<1, 256, 0, stream>>>(bsum, nb);
    scanC_kernel<<<nb, 256, 0, stream>>>(off, cur, bsum, N, E);
    scatter_kernel<<<2048, 256, 0, stream>>>(src, dst, cur, ssrc, E);
    agg_kernel<<<2048, 256, 0, stream>>>(ft, off, ssrc, W_pi, out, N);
}

// Round 9
// 229.206 us; speedup vs baseline: 1.1809x; 1.0352x over previous
//
#include <hip/hip_runtime.h>
#include <math.h>

#define DIM 64
#define FDIM 256   // DIM * H (H=4)
#define DEFER_THR 4.0f

typedef _Float16 h2 __attribute__((ext_vector_type(2)));
typedef float f2 __attribute__((ext_vector_type(2)));

// ---------------- Stage 1: ft = f16(h_v @ W_fc^T + b_fc)  -> [N, 256] ----------------
// Thread t owns output column t; h-row values are wave-uniform (L1/scalar broadcast).
__global__ __launch_bounds__(256) void fc_kernel(const float* __restrict__ h,
                                                 const float* __restrict__ W,
                                                 const float* __restrict__ b,
                                                 _Float16* __restrict__ ft, int N)
{
    int t = threadIdx.x;              // output column 0..255
    float w[DIM];
#pragma unroll
    for (int j = 0; j < DIM / 4; ++j) {
        float4 v = *(const float4*)(W + (size_t)t * DIM + j * 4);
        w[4 * j + 0] = v.x; w[4 * j + 1] = v.y;
        w[4 * j + 2] = v.z; w[4 * j + 3] = v.w;
    }
    float bt = b[t];
    for (int r = blockIdx.x; r < N; r += gridDim.x) {
        const float4* h4 = (const float4*)(h + (size_t)r * DIM);
        float acc = bt;
#pragma unroll
        for (int j = 0; j < DIM / 4; ++j) {
            float4 hv = h4[j];       // uniform address across the wave
            acc = fmaf(hv.x, w[4 * j + 0], acc);
            acc = fmaf(hv.y, w[4 * j + 1], acc);
            acc = fmaf(hv.z, w[4 * j + 2], acc);
            acc = fmaf(hv.w, w[4 * j + 3], acc);
        }
        ft[(size_t)r * FDIM + t] = (_Float16)acc;
    }
}

// ---------------- Counting sort of edges by dst ----------------
__global__ void zero_kernel(int* __restrict__ p, int n)
{
    int i = blockIdx.x * blockDim.x + threadIdx.x;
    for (; i < n; i += gridDim.x * blockDim.x) p[i] = 0;
}

__global__ void hist_kernel(const int* __restrict__ dst, int* __restrict__ cnt, int E)
{
    int i = blockIdx.x * blockDim.x + threadIdx.x;
    for (; i < E; i += gridDim.x * blockDim.x) atomicAdd(&cnt[dst[i]], 1);
}

// ---------------- Multi-block exclusive scan of cnt[0..N) ----------------
__global__ __launch_bounds__(256) void scanA_kernel(const int* __restrict__ cnt,
                                                    int* __restrict__ off,
                                                    int* __restrict__ bsum, int N)
{
    __shared__ int sh[256];
    int t = threadIdx.x;
    int i = blockIdx.x * 256 + t;
    int v = (i < N) ? cnt[i] : 0;
    sh[t] = v;
    __syncthreads();
#pragma unroll
    for (int o = 1; o < 256; o <<= 1) {
        int x = (t >= o) ? sh[t - o] : 0;
        __syncthreads();
        sh[t] += x;
        __syncthreads();
    }
    if (i < N) off[i] = sh[t] - v;          // local exclusive
    if (t == 255) bsum[blockIdx.x] = sh[255];
}

__global__ __launch_bounds__(256) void scanB_kernel(int* __restrict__ bsum, int nb)
{
    __shared__ int sh[256];
    int t = threadIdx.x;
    int carry = 0;
    for (int base = 0; base < nb; base += 256) {
        int i = base + t;
        int v = (i < nb) ? bsum[i] : 0;
        sh[t] = v;
        __syncthreads();
#pragma unroll
        for (int o = 1; o < 256; o <<= 1) {
            int x = (t >= o) ? sh[t - o] : 0;
            __syncthreads();
            sh[t] += x;
            __syncthreads();
        }
        if (i < nb) bsum[i] = carry + sh[t] - v;   // exclusive
        int tot = sh[255];
        __syncthreads();
        carry += tot;
    }
}

__global__ void scanC_kernel(int* __restrict__ off, int* __restrict__ cur,
                             const int* __restrict__ bsum, int N, int E)
{
    int i = blockIdx.x * blockDim.x + threadIdx.x;
    if (i < N) {
        int v = off[i] + bsum[i >> 8];
        off[i] = v;
        cur[i] = v;
    }
    if (i == 0) off[N] = E;
}

__global__ void scatter_kernel(const int* __restrict__ src, const int* __restrict__ dst,
                               int* __restrict__ cur, int* __restrict__ ssrc, int E)
{
    int i = blockIdx.x * blockDim.x + threadIdx.x;
    for (; i < E; i += gridDim.x * blockDim.x) {
        int d = dst[i];
        int pos = atomicAdd(&cur[d], 1);
        ssrc[pos] = src[i];
    }
}

// ---------------- Fused: score + edge-softmax + weighted sum + head-max ----------------
// Persistent waves; one wave per node, 4 edges/iter, software-pipelined 1 ahead.
// Quarter q (16 lanes) owns edge base+q with its OWN online softmax (m_q,l_q,acc_q);
// states merged at the epilogue. Lane ql owns dims 16*ql..16*ql+15.
// ft is f16; dot via v_dot2_f32_f16, accumulate via packed f32 fma.
__global__ __launch_bounds__(256) void agg_kernel(const _Float16* __restrict__ ft,
                                                  const int* __restrict__ off,
                                                  const int* __restrict__ ssrc,
                                                  const float* __restrict__ Wpi,
                                                  float* __restrict__ out, int N)
{
    int nwaves = gridDim.x * (blockDim.x >> 6);
    int gw = blockIdx.x * (blockDim.x >> 6) + (threadIdx.x >> 6);
    int lane = threadIdx.x & 63;
    int q  = lane >> 4;
    int ql = lane & 15;

    // Wpi slice for this lane's 16 dims (node-independent, hoisted)
    float wq[16];
    {
        const float4* wp4 = (const float4*)(Wpi + ql * 16);
#pragma unroll
        for (int j = 0; j < 4; ++j) {
            float4 w = wp4[j];
            wq[4 * j + 0] = w.x; wq[4 * j + 1] = w.y;
            wq[4 * j + 2] = w.z; wq[4 * j + 3] = w.w;
        }
    }

    for (int wid = gw; wid < N; wid += nwaves) {
        // fdwh[k] = f16( ft[wid][16*ql+2k..2k+1] * Wpi[...] )
        h2 fdwh[8];
        {
            const _Float16* drow = ft + (size_t)wid * FDIM + ql * 16;
            uint4 a = *(const uint4*)(drow);
            uint4 b = *(const uint4*)(drow + 8);
            const h2* da = (const h2*)&a;
            const h2* db = (const h2*)&b;
#pragma unroll
            for (int j = 0; j < 4; ++j) {
                h2 v = da[j];
                fdwh[j].x = (_Float16)((float)v.x * wq[2 * j + 0]);
                fdwh[j].y = (_Float16)((float)v.y * wq[2 * j + 1]);
                h2 u = db[j];
                fdwh[4 + j].x = (_Float16)((float)u.x * wq[8 + 2 * j + 0]);
                fdwh[4 + j].y = (_Float16)((float)u.y * wq[8 + 2 * j + 1]);
            }
        }

        int e0 = off[wid], e1 = off[wid + 1];
        float mq = -INFINITY, lq = 0.f;
        f2 acc2[8];
#pragma unroll
        for (int j = 0; j < 8; ++j) acc2[j] = (f2){0.f, 0.f};

        auto LOAD = [&](uint4& ra, uint4& rb, bool& val, int bse) {
            int ei = bse + q;
            val = ei < e1;
            int sv = ssrc[val ? ei : bse];
            const _Float16* srow = ft + (size_t)sv * FDIM + ql * 16;
            ra = *(const uint4*)(srow);
            rb = *(const uint4*)(srow + 8);
        };
        auto COMP = [&](uint4 ra, uint4 rb, bool val) {
            const h2* fa = (const h2*)&ra;
            const h2* fb = (const h2*)&rb;
            float p = 0.f;
#pragma unroll
            for (int j = 0; j < 4; ++j) p = __builtin_amdgcn_fdot2(fa[j], fdwh[j], p, false);
#pragma unroll
            for (int j = 0; j < 4; ++j) p = __builtin_amdgcn_fdot2(fb[j], fdwh[4 + j], p, false);
            p += __shfl_xor(p, 1, 64);
            p += __shfl_xor(p, 2, 64);
            p += __shfl_xor(p, 4, 64);
            p += __shfl_xor(p, 8, 64);
            float s = p > 0.f ? p : 0.2f * p;       // LeakyReLU(0.2)
            if (val) {                               // quarter-divergent
                if (s > mq + DEFER_THR) {            // T13 defer-max; first edge: -inf -> taken
                    float sc = __expf(mq - s);       // first: exp(-inf)=0
                    lq *= sc;
                    f2 sc2 = {sc, sc};
#pragma unroll
                    for (int j = 0; j < 8; ++j) acc2[j] *= sc2;
                    mq = s;
                }
                float pe = __expf(s - mq);           // bounded by e^THR
                lq += pe;
                f2 pe2 = {pe, pe};
#pragma unroll
                for (int j = 0; j < 4; ++j) {
                    f2 v0 = {(float)fa[j].x, (float)fa[j].y};
                    acc2[j] = __builtin_elementwise_fma(pe2, v0, acc2[j]);
                    f2 v1 = {(float)fb[j].x, (float)fb[j].y};
                    acc2[4 + j] = __builtin_elementwise_fma(pe2, v1, acc2[4 + j]);
                }
            }
        };

        if (e0 < e1) {
            uint4 Aa, Ab, Ba, Bb;
            bool Av = false, Bv = false;
            int base = e0;
            LOAD(Aa, Ab, Av, base);
            while (true) {
                int nxt = base + 4;
                if (nxt < e1) LOAD(Ba, Bb, Bv, nxt);
                COMP(Aa, Ab, Av);
                base = nxt;
                if (base >= e1) break;
                nxt = base + 4;
                if (nxt < e1) LOAD(Aa, Ab, Av, nxt);
                COMP(Ba, Bb, Bv);
                base = nxt;
                if (base >= e1) break;
            }
        }

        // merge 4 quarter softmax states
        float mstar = fmaxf(mq, __shfl_xor(mq, 16, 64));
        mstar = fmaxf(mstar, __shfl_xor(mstar, 32, 64));
        float sc = (lq > 0.f) ? __expf(mq - mstar) : 0.f;
        float lt = lq * sc;
        lt += __shfl_xor(lt, 16, 64);
        lt += __shfl_xor(lt, 32, 64);
        float inv = (lt > 0.f) ? 1.f / lt : 0.f;

        // quarter-sum, head-max (head = ql>>2 -> xor lane bits 2,3), normalize
        float r[16];
#pragma unroll
        for (int j = 0; j < 8; ++j) {
#pragma unroll
            for (int k = 0; k < 2; ++k) {
                float v = acc2[j][k] * sc;
                v += __shfl_xor(v, 16, 64);
                v += __shfl_xor(v, 32, 64);
                v = fmaxf(v, __shfl_xor(v, 4, 64));
                v = fmaxf(v, __shfl_xor(v, 8, 64));
                r[2 * j + k] = v * inv;
            }
        }
        if (lane < 4) {                              // q==0, ql 0..3: dims 16*ql..16*ql+15
            float4* o4 = (float4*)(out + (size_t)wid * DIM + ql * 16);
            o4[0] = make_float4(r[0],  r[1],  r[2],  r[3]);
            o4[1] = make_float4(r[4],  r[5],  r[6],  r[7]);
            o4[2] = make_float4(r[8],  r[9],  r[10], r[11]);
            o4[3] = make_float4(r[12], r[13], r[14], r[15]);
        }
    }
}

extern "C" void kernel_launch(void* const* d_in, const int* in_sizes, int n_in,
                              void* d_out, int out_size, void* d_ws, size_t ws_size,
                              hipStream_t stream)
{
    const float* h_v  = (const float*)d_in[0];
    const int*   src  = (const int*)d_in[1];
    const int*   dst  = (const int*)d_in[2];
    const float* W_fc = (const float*)d_in[3];
    const float* b_fc = (const float*)d_in[4];
    const float* W_pi = (const float*)d_in[5];
    float* out = (float*)d_out;

    int N = in_sizes[0] / DIM;
    int E = in_sizes[1];

    // workspace layout
    _Float16* ft = (_Float16*)d_ws;                        // N*256*2 = 25.6 MB
    size_t ftB = (((size_t)N * FDIM * 2) + 255) & ~(size_t)255;
    char*  p    = (char*)d_ws + ftB;
    int*   cnt  = (int*)(p);                               // N
    int*   off  = (int*)(p + 256 * 1024);                  // N+1
    int*   cur  = (int*)(p + 512 * 1024);                  // N
    int*   bsum = (int*)(p + 768 * 1024);                  // ceil(N/256)
    int*   ssrc = (int*)(p + 1024 * 1024);                 // E

    int nb = (N + 255) / 256;
    fc_kernel<<<1024, 256, 0, stream>>>(h_v, W_fc, b_fc, ft, N);
    zero_kernel<<<256, 256, 0, stream>>>(cnt, N);
    hist_kernel<<<1024, 256, 0, stream>>>(dst, cnt, E);
    scanA_kernel<<<nb, 256, 0, stream>>>(cnt, off, bsum, N);
    scanB_kernel<<<1, 256, 0, stream>>>(bsum, nb);
    scanC_kernel<<<nb, 256, 0, stream>>>(off, cur, bsum, N, E);
    scatter_kernel<<<1024, 256, 0, stream>>>(src, dst, cur, ssrc, E);
    agg_kernel<<<2048, 256, 0, stream>>>(ft, off, ssrc, W_pi, out, N);
}

// Round 10
// 208.102 us; speedup vs baseline: 1.3007x; 1.1014x over previous
//
#include <hip/hip_runtime.h>
#include <math.h>

#define DIM 64
#define FDIM 256   // DIM * H (H=4)
#define DEFER_THR 4.0f

typedef _Float16 h2 __attribute__((ext_vector_type(2)));
typedef float f2 __attribute__((ext_vector_type(2)));

// ---------------- Stage 1: ft = f16(h_v @ W_fc^T + b_fc)  -> [N, 256] ----------------
__global__ __launch_bounds__(256) void fc_kernel(const float* __restrict__ h,
                                                 const float* __restrict__ W,
                                                 const float* __restrict__ b,
                                                 _Float16* __restrict__ ft, int N)
{
    int t = threadIdx.x;              // output column 0..255
    float w[DIM];
#pragma unroll
    for (int j = 0; j < DIM / 4; ++j) {
        float4 v = *(const float4*)(W + (size_t)t * DIM + j * 4);
        w[4 * j + 0] = v.x; w[4 * j + 1] = v.y;
        w[4 * j + 2] = v.z; w[4 * j + 3] = v.w;
    }
    float bt = b[t];
    for (int r = blockIdx.x; r < N; r += gridDim.x) {
        const float4* h4 = (const float4*)(h + (size_t)r * DIM);
        float acc = bt;
#pragma unroll
        for (int j = 0; j < DIM / 4; ++j) {
            float4 hv = h4[j];       // uniform address across the wave
            acc = fmaf(hv.x, w[4 * j + 0], acc);
            acc = fmaf(hv.y, w[4 * j + 1], acc);
            acc = fmaf(hv.z, w[4 * j + 2], acc);
            acc = fmaf(hv.w, w[4 * j + 3], acc);
        }
        ft[(size_t)r * FDIM + t] = (_Float16)acc;
    }
}

// ---------------- Counting sort of edges by dst ----------------
__global__ void zero_kernel(int* __restrict__ p, int n)
{
    int i = blockIdx.x * blockDim.x + threadIdx.x;
    for (; i < n; i += gridDim.x * blockDim.x) p[i] = 0;
}

__global__ void hist_kernel(const int* __restrict__ dst, int* __restrict__ cnt, int E)
{
    int i = blockIdx.x * blockDim.x + threadIdx.x;
    for (; i < E; i += gridDim.x * blockDim.x) atomicAdd(&cnt[dst[i]], 1);
}

__global__ __launch_bounds__(256) void scanA_kernel(const int* __restrict__ cnt,
                                                    int* __restrict__ off,
                                                    int* __restrict__ bsum, int N)
{
    __shared__ int sh[256];
    int t = threadIdx.x;
    int i = blockIdx.x * 256 + t;
    int v = (i < N) ? cnt[i] : 0;
    sh[t] = v;
    __syncthreads();
#pragma unroll
    for (int o = 1; o < 256; o <<= 1) {
        int x = (t >= o) ? sh[t - o] : 0;
        __syncthreads();
        sh[t] += x;
        __syncthreads();
    }
    if (i < N) off[i] = sh[t] - v;          // local exclusive
    if (t == 255) bsum[blockIdx.x] = sh[255];
}

__global__ __launch_bounds__(256) void scanB_kernel(int* __restrict__ bsum, int nb)
{
    __shared__ int sh[256];
    int t = threadIdx.x;
    int carry = 0;
    for (int base = 0; base < nb; base += 256) {
        int i = base + t;
        int v = (i < nb) ? bsum[i] : 0;
        sh[t] = v;
        __syncthreads();
#pragma unroll
        for (int o = 1; o < 256; o <<= 1) {
            int x = (t >= o) ? sh[t - o] : 0;
            __syncthreads();
            sh[t] += x;
            __syncthreads();
        }
        if (i < nb) bsum[i] = carry + sh[t] - v;   // exclusive
        int tot = sh[255];
        __syncthreads();
        carry += tot;
    }
}

__global__ void scanC_kernel(int* __restrict__ off, int* __restrict__ cur,
                             const int* __restrict__ bsum, int N, int E)
{
    int i = blockIdx.x * blockDim.x + threadIdx.x;
    if (i < N) {
        int v = off[i] + bsum[i >> 8];
        off[i] = v;
        cur[i] = v;
    }
    if (i == 0) off[N] = E;
}

__global__ void scatter_kernel(const int* __restrict__ src, const int* __restrict__ dst,
                               int* __restrict__ cur, int* __restrict__ ssrc, int E)
{
    int i = blockIdx.x * blockDim.x + threadIdx.x;
    for (; i < E; i += gridDim.x * blockDim.x) {
        int d = dst[i];
        int pos = atomicAdd(&cur[d], 1);
        ssrc[pos] = src[i];
    }
}

// ---------------- Fused: score + edge-softmax + weighted sum + head-max ----------------
// One wave per node. 8 edges/iter: quarter q owns edges base+q and base+q+4, each quarter
// keeps an independent online softmax (mq,lq,acc); 1 pack prefetched ahead.
// Epilogue: LDS transpose (padded, conflict-free) -> sum over quarters + max over heads
// in-register -> fully coalesced 64-lane store.
__global__ __launch_bounds__(256) void agg_kernel(const _Float16* __restrict__ ft,
                                                  const int* __restrict__ off,
                                                  const int* __restrict__ ssrc,
                                                  const float* __restrict__ Wpi,
                                                  float* __restrict__ out, int N)
{
    __shared__ float xb[4][1280];     // per-wave 64 lanes * 20 words (padded 16->20)
    int wid = (blockIdx.x * blockDim.x + threadIdx.x) >> 6;
    int wv  = threadIdx.x >> 6;       // wave within block
    int lane = threadIdx.x & 63;
    if (wid >= N) return;
    int q  = lane >> 4;
    int ql = lane & 15;

    // fdwh[k] = f16( ft[wid][16*ql+2k..2k+1] * Wpi[...] )
    h2 fdwh[8];
    {
        const float4* wp4 = (const float4*)(Wpi + ql * 16);
        const _Float16* drow = ft + (size_t)wid * FDIM + ql * 16;
        uint4 a = *(const uint4*)(drow);
        uint4 b = *(const uint4*)(drow + 8);
        const h2* da = (const h2*)&a;
        const h2* db = (const h2*)&b;
#pragma unroll
        for (int j = 0; j < 4; ++j) {
            float4 w0 = wp4[j];
            h2 v = da[j], u = db[j];
            if (j < 2) { }
            fdwh[j].x     = (_Float16)((float)v.x * ((const float*)&w0)[0]);
            fdwh[j].y     = (_Float16)((float)v.y * ((const float*)&w0)[1]);
            fdwh[4 + j].x = (_Float16)((float)u.x * ((const float*)(wp4 + 2) + 2 * j)[0]);
            fdwh[4 + j].y = (_Float16)((float)u.y * ((const float*)(wp4 + 2) + 2 * j)[1]);
            // fix low half pairs 2..3
            fdwh[j].x = (_Float16)((float)v.x * ((const float*)wp4)[2 * j + 0]);
            fdwh[j].y = (_Float16)((float)v.y * ((const float*)wp4)[2 * j + 1]);
            fdwh[4 + j].x = (_Float16)((float)u.x * ((const float*)wp4)[8 + 2 * j + 0]);
            fdwh[4 + j].y = (_Float16)((float)u.y * ((const float*)wp4)[8 + 2 * j + 1]);
        }
    }

    int e0 = off[wid], e1 = off[wid + 1];
    float mq = -INFINITY, lq = 0.f;
    f2 acc2[8];
#pragma unroll
    for (int j = 0; j < 8; ++j) acc2[j] = (f2){0.f, 0.f};

    auto LOAD8 = [&](uint4& a1, uint4& b1, uint4& a2, uint4& b2,
                     bool& v1, bool& v2, int bse) {
        int lo = bse + q, hi = bse + q + 4;
        v1 = lo < e1; v2 = hi < e1;
        int s1 = ssrc[v1 ? lo : e0];
        int s2 = ssrc[v2 ? hi : e0];
        const _Float16* r1 = ft + (size_t)s1 * FDIM + ql * 16;
        const _Float16* r2 = ft + (size_t)s2 * FDIM + ql * 16;
        a1 = *(const uint4*)(r1);
        b1 = *(const uint4*)(r1 + 8);
        a2 = *(const uint4*)(r2);
        b2 = *(const uint4*)(r2 + 8);
    };
    auto COMP8 = [&](uint4 a1, uint4 b1, uint4 a2, uint4 b2, bool v1, bool v2) {
        const h2* fa1 = (const h2*)&a1; const h2* fb1 = (const h2*)&b1;
        const h2* fa2 = (const h2*)&a2; const h2* fb2 = (const h2*)&b2;
        float p1 = 0.f, p2 = 0.f;
#pragma unroll
        for (int j = 0; j < 4; ++j) {
            p1 = __builtin_amdgcn_fdot2(fa1[j], fdwh[j], p1, false);
            p2 = __builtin_amdgcn_fdot2(fa2[j], fdwh[j], p2, false);
        }
#pragma unroll
        for (int j = 0; j < 4; ++j) {
            p1 = __builtin_amdgcn_fdot2(fb1[j], fdwh[4 + j], p1, false);
            p2 = __builtin_amdgcn_fdot2(fb2[j], fdwh[4 + j], p2, false);
        }
        p1 += __shfl_xor(p1, 1, 64);  p2 += __shfl_xor(p2, 1, 64);
        p1 += __shfl_xor(p1, 2, 64);  p2 += __shfl_xor(p2, 2, 64);
        p1 += __shfl_xor(p1, 4, 64);  p2 += __shfl_xor(p2, 4, 64);
        p1 += __shfl_xor(p1, 8, 64);  p2 += __shfl_xor(p2, 8, 64);
        float s1 = p1 > 0.f ? p1 : 0.2f * p1;     // LeakyReLU(0.2)
        float s2 = p2 > 0.f ? p2 : 0.2f * p2;
        if (!v1) s1 = -INFINITY;
        if (!v2) s2 = -INFINITY;
        float smax = fmaxf(s1, s2);
        if (smax > mq + DEFER_THR) {              // first valid edge: -inf -> taken
            float sc = __expf(mq - smax);         // first: exp(-inf)=0
            lq *= sc;
            f2 sc2 = {sc, sc};
#pragma unroll
            for (int j = 0; j < 8; ++j) acc2[j] *= sc2;
            mq = smax;
        }
        float pe1 = v1 ? __expf(s1 - mq) : 0.f;   // bounded by e^THR
        float pe2 = v2 ? __expf(s2 - mq) : 0.f;
        lq += pe1 + pe2;
        f2 pe1v = {pe1, pe1}, pe2v = {pe2, pe2};
#pragma unroll
        for (int j = 0; j < 4; ++j) {
            f2 w1 = {(float)fa1[j].x, (float)fa1[j].y};
            f2 w2 = {(float)fa2[j].x, (float)fa2[j].y};
            acc2[j] = __builtin_elementwise_fma(pe1v, w1,
                       __builtin_elementwise_fma(pe2v, w2, acc2[j]));
            f2 u1 = {(float)fb1[j].x, (float)fb1[j].y};
            f2 u2 = {(float)fb2[j].x, (float)fb2[j].y};
            acc2[4 + j] = __builtin_elementwise_fma(pe1v, u1,
                           __builtin_elementwise_fma(pe2v, u2, acc2[4 + j]));
        }
    };

    if (e0 < e1) {
        uint4 Aa1, Ab1, Aa2, Ab2, Ba1, Bb1, Ba2, Bb2;
        bool Av1, Av2, Bv1, Bv2;
        int base = e0;
        LOAD8(Aa1, Ab1, Aa2, Ab2, Av1, Av2, base);
        while (true) {
            int nxt = base + 8;
            bool more = nxt < e1;
            if (more) LOAD8(Ba1, Bb1, Ba2, Bb2, Bv1, Bv2, nxt);
            COMP8(Aa1, Ab1, Aa2, Ab2, Av1, Av2);
            if (!more) break;
            base = nxt;
            nxt = base + 8;
            more = nxt < e1;
            if (more) LOAD8(Aa1, Ab1, Aa2, Ab2, Av1, Av2, nxt);
            COMP8(Ba1, Bb1, Ba2, Bb2, Bv1, Bv2);
            if (!more) break;
            base = nxt;
        }
    }

    // ---- merge quarter states (4 shuffles total) ----
    float mstar = fmaxf(mq, __shfl_xor(mq, 16, 64));
    mstar = fmaxf(mstar, __shfl_xor(mstar, 32, 64));
    float sc = (lq > 0.f) ? __expf(mq - mstar) : 0.f;
    float lt = lq * sc;
    lt += __shfl_xor(lt, 16, 64);
    lt += __shfl_xor(lt, 32, 64);
    float inv = (lt > 0.f) ? 1.f / lt : 0.f;

    // ---- LDS transpose epilogue ----
    // write 16 scaled values at padded stride 20 words (byte 80*lane: 16B aligned,
    // bank histogram uniform -> conflict-free b128 writes)
    {
        float* wp = &xb[wv][(unsigned)lane * 20];
        f2 sc2 = {sc, sc};
#pragma unroll
        for (int k = 0; k < 4; ++k) {
            f2 lo = acc2[2 * k] * sc2;
            f2 hi = acc2[2 * k + 1] * sc2;
            *(float4*)(wp + 4 * k) = make_float4(lo.x, lo.y, hi.x, hi.y);
        }
    }
    asm volatile("s_waitcnt lgkmcnt(0)" ::: "memory");
    // lane L -> output dim d=L: col=d>>4, jp=d&15;
    // sum over q of V[q][col+4h][jp], then max over heads h
    {
        int col = lane >> 4, jp = lane & 15;
        float A[4];
#pragma unroll
        for (int h = 0; h < 4; ++h) {
            int rowb = (col + 4 * h) * 20 + jp;
            float v0 = xb[wv][rowb];
            float v1 = xb[wv][rowb + 16 * 20];
            float v2 = xb[wv][rowb + 32 * 20];
            float v3 = xb[wv][rowb + 48 * 20];
            A[h] = (v0 + v1) + (v2 + v3);
        }
        float r = fmaxf(fmaxf(A[0], A[1]), fmaxf(A[2], A[3])) * inv;
        out[(size_t)wid * DIM + lane] = r;
    }
}

extern "C" void kernel_launch(void* const* d_in, const int* in_sizes, int n_in,
                              void* d_out, int out_size, void* d_ws, size_t ws_size,
                              hipStream_t stream)
{
    const float* h_v  = (const float*)d_in[0];
    const int*   src  = (const int*)d_in[1];
    const int*   dst  = (const int*)d_in[2];
    const float* W_fc = (const float*)d_in[3];
    const float* b_fc = (const float*)d_in[4];
    const float* W_pi = (const float*)d_in[5];
    float* out = (float*)d_out;

    int N = in_sizes[0] / DIM;
    int E = in_sizes[1];

    // workspace layout
    _Float16* ft = (_Float16*)d_ws;                        // N*256*2 = 25.6 MB
    size_t ftB = (((size_t)N * FDIM * 2) + 255) & ~(size_t)255;
    char*  p    = (char*)d_ws + ftB;
    int*   cnt  = (int*)(p);                               // N
    int*   off  = (int*)(p + 256 * 1024);                  // N+1
    int*   cur  = (int*)(p + 512 * 1024);                  // N
    int*   bsum = (int*)(p + 768 * 1024);                  // ceil(N/256)
    int*   ssrc = (int*)(p + 1024 * 1024);                 // E

    int nb = (N + 255) / 256;
    fc_kernel<<<1024, 256, 0, stream>>>(h_v, W_fc, b_fc, ft, N);
    zero_kernel<<<256, 256, 0, stream>>>(cnt, N);
    hist_kernel<<<1024, 256, 0, stream>>>(dst, cnt, E);
    scanA_kernel<<<nb, 256, 0, stream>>>(cnt, off, bsum, N);
    scanB_kernel<<<1, 256, 0, stream>>>(bsum, nb);
    scanC_kernel<<<nb, 256, 0, stream>>>(off, cur, bsum, N, E);
    scatter_kernel<<<1024, 256, 0, stream>>>(src, dst, cur, ssrc, E);
    int blocks = (N * 64 + 255) / 256;   // one 64-lane wave per node
    agg_kernel<<<blocks, 256, 0, stream>>>(ft, off, ssrc, W_pi, out, N);
}

// Round 11
// 197.921 us; speedup vs baseline: 1.3676x; 1.0514x over previous
//
#include <hip/hip_runtime.h>
#include <math.h>

#define DIM 64
#define FDIM 256   // DIM * H (H=4)
#define DEFER_THR 4.0f

typedef _Float16 h2 __attribute__((ext_vector_type(2)));
typedef float f2 __attribute__((ext_vector_type(2)));

// ---------------- Stage 1: ft = f16(h_v @ W_fc^T + b_fc)  -> [N, 256] ----------------
__global__ __launch_bounds__(256) void fc_kernel(const float* __restrict__ h,
                                                 const float* __restrict__ W,
                                                 const float* __restrict__ b,
                                                 _Float16* __restrict__ ft, int N)
{
    int t = threadIdx.x;              // output column 0..255
    float w[DIM];
#pragma unroll
    for (int j = 0; j < DIM / 4; ++j) {
        float4 v = *(const float4*)(W + (size_t)t * DIM + j * 4);
        w[4 * j + 0] = v.x; w[4 * j + 1] = v.y;
        w[4 * j + 2] = v.z; w[4 * j + 3] = v.w;
    }
    float bt = b[t];
    for (int r = blockIdx.x; r < N; r += gridDim.x) {
        const float4* h4 = (const float4*)(h + (size_t)r * DIM);
        float acc = bt;
#pragma unroll
        for (int j = 0; j < DIM / 4; ++j) {
            float4 hv = h4[j];       // uniform address across the wave
            acc = fmaf(hv.x, w[4 * j + 0], acc);
            acc = fmaf(hv.y, w[4 * j + 1], acc);
            acc = fmaf(hv.z, w[4 * j + 2], acc);
            acc = fmaf(hv.w, w[4 * j + 3], acc);
        }
        ft[(size_t)r * FDIM + t] = (_Float16)acc;
    }
}

// ---------------- Counting sort of edges by dst ----------------
__global__ void zero_kernel(int* __restrict__ p, int n)
{
    int i = blockIdx.x * blockDim.x + threadIdx.x;
    for (; i < n; i += gridDim.x * blockDim.x) p[i] = 0;
}

// 1 edge per thread (exact-cover grid): every atomic chain independent.
__global__ void hist_kernel(const int* __restrict__ dst, int* __restrict__ cnt, int E)
{
    int i = blockIdx.x * blockDim.x + threadIdx.x;
    if (i < E) atomicAdd(&cnt[dst[i]], 1);
}

__global__ __launch_bounds__(256) void scanA_kernel(const int* __restrict__ cnt,
                                                    int* __restrict__ off,
                                                    int* __restrict__ bsum, int N)
{
    __shared__ int sh[256];
    int t = threadIdx.x;
    int i = blockIdx.x * 256 + t;
    int v = (i < N) ? cnt[i] : 0;
    sh[t] = v;
    __syncthreads();
#pragma unroll
    for (int o = 1; o < 256; o <<= 1) {
        int x = (t >= o) ? sh[t - o] : 0;
        __syncthreads();
        sh[t] += x;
        __syncthreads();
    }
    if (i < N) off[i] = sh[t] - v;          // local exclusive
    if (t == 255) bsum[blockIdx.x] = sh[255];
}

__global__ __launch_bounds__(256) void scanB_kernel(int* __restrict__ bsum, int nb)
{
    __shared__ int sh[256];
    int t = threadIdx.x;
    int carry = 0;
    for (int base = 0; base < nb; base += 256) {
        int i = base + t;
        int v = (i < nb) ? bsum[i] : 0;
        sh[t] = v;
        __syncthreads();
#pragma unroll
        for (int o = 1; o < 256; o <<= 1) {
            int x = (t >= o) ? sh[t - o] : 0;
            __syncthreads();
            sh[t] += x;
            __syncthreads();
        }
        if (i < nb) bsum[i] = carry + sh[t] - v;   // exclusive
        int tot = sh[255];
        __syncthreads();
        carry += tot;
    }
}

__global__ void scanC_kernel(int* __restrict__ off, int* __restrict__ cur,
                             const int* __restrict__ bsum, int N, int E)
{
    int i = blockIdx.x * blockDim.x + threadIdx.x;
    if (i < N) {
        int v = off[i] + bsum[i >> 8];
        off[i] = v;
        cur[i] = v;
    }
    if (i == 0) off[N] = E;
}

// 1 edge per thread (exact-cover grid).
__global__ void scatter_kernel(const int* __restrict__ src, const int* __restrict__ dst,
                               int* __restrict__ cur, int* __restrict__ ssrc, int E)
{
    int i = blockIdx.x * blockDim.x + threadIdx.x;
    if (i < E) {
        int d = dst[i];
        int pos = atomicAdd(&cur[d], 1);
        ssrc[pos] = src[i];
    }
}

// ---------------- Fused: score + edge-softmax + weighted sum + head-max ----------------
// One wave per node. 8 edges/iter: quarter q owns edges base+q and base+q+4, each quarter
// keeps an independent online softmax (mq,lq,acc); 1 pack prefetched ahead.
// Epilogue: LDS transpose (padded, conflict-free) -> sum over quarters + max over heads
// in-register -> fully coalesced 64-lane store.
__global__ __launch_bounds__(256) void agg_kernel(const _Float16* __restrict__ ft,
                                                  const int* __restrict__ off,
                                                  const int* __restrict__ ssrc,
                                                  const float* __restrict__ Wpi,
                                                  float* __restrict__ out, int N)
{
    __shared__ float xb[4][1280];     // per-wave 64 lanes * 20 words (padded 16->20)
    int wid = (blockIdx.x * blockDim.x + threadIdx.x) >> 6;
    int wv  = threadIdx.x >> 6;       // wave within block
    int lane = threadIdx.x & 63;
    if (wid >= N) return;
    int q  = lane >> 4;
    int ql = lane & 15;

    // fdwh[k] = f16( ft[wid][16*ql+2k..2k+1] * Wpi[...] )
    h2 fdwh[8];
    {
        const float* wp = Wpi + ql * 16;
        const _Float16* drow = ft + (size_t)wid * FDIM + ql * 16;
        uint4 a = *(const uint4*)(drow);
        uint4 b = *(const uint4*)(drow + 8);
        const h2* da = (const h2*)&a;
        const h2* db = (const h2*)&b;
#pragma unroll
        for (int j = 0; j < 4; ++j) {
            h2 v = da[j], u = db[j];
            fdwh[j].x     = (_Float16)((float)v.x * wp[2 * j + 0]);
            fdwh[j].y     = (_Float16)((float)v.y * wp[2 * j + 1]);
            fdwh[4 + j].x = (_Float16)((float)u.x * wp[8 + 2 * j + 0]);
            fdwh[4 + j].y = (_Float16)((float)u.y * wp[8 + 2 * j + 1]);
        }
    }

    int e0 = off[wid], e1 = off[wid + 1];
    float mq = -INFINITY, lq = 0.f;
    f2 acc2[8];
#pragma unroll
    for (int j = 0; j < 8; ++j) acc2[j] = (f2){0.f, 0.f};

    auto LOAD8 = [&](uint4& a1, uint4& b1, uint4& a2, uint4& b2,
                     bool& v1, bool& v2, int bse) {
        int lo = bse + q, hi = bse + q + 4;
        v1 = lo < e1; v2 = hi < e1;
        int s1 = ssrc[v1 ? lo : e0];
        int s2 = ssrc[v2 ? hi : e0];
        const _Float16* r1 = ft + (size_t)s1 * FDIM + ql * 16;
        const _Float16* r2 = ft + (size_t)s2 * FDIM + ql * 16;
        a1 = *(const uint4*)(r1);
        b1 = *(const uint4*)(r1 + 8);
        a2 = *(const uint4*)(r2);
        b2 = *(const uint4*)(r2 + 8);
    };
    auto COMP8 = [&](uint4 a1, uint4 b1, uint4 a2, uint4 b2, bool v1, bool v2) {
        const h2* fa1 = (const h2*)&a1; const h2* fb1 = (const h2*)&b1;
        const h2* fa2 = (const h2*)&a2; const h2* fb2 = (const h2*)&b2;
        float p1 = 0.f, p2 = 0.f;
#pragma unroll
        for (int j = 0; j < 4; ++j) {
            p1 = __builtin_amdgcn_fdot2(fa1[j], fdwh[j], p1, false);
            p2 = __builtin_amdgcn_fdot2(fa2[j], fdwh[j], p2, false);
        }
#pragma unroll
        for (int j = 0; j < 4; ++j) {
            p1 = __builtin_amdgcn_fdot2(fb1[j], fdwh[4 + j], p1, false);
            p2 = __builtin_amdgcn_fdot2(fb2[j], fdwh[4 + j], p2, false);
        }
        p1 += __shfl_xor(p1, 1, 64);  p2 += __shfl_xor(p2, 1, 64);
        p1 += __shfl_xor(p1, 2, 64);  p2 += __shfl_xor(p2, 2, 64);
        p1 += __shfl_xor(p1, 4, 64);  p2 += __shfl_xor(p2, 4, 64);
        p1 += __shfl_xor(p1, 8, 64);  p2 += __shfl_xor(p2, 8, 64);
        float s1 = p1 > 0.f ? p1 : 0.2f * p1;     // LeakyReLU(0.2)
        float s2 = p2 > 0.f ? p2 : 0.2f * p2;
        if (!v1) s1 = -INFINITY;
        if (!v2) s2 = -INFINITY;
        float smax = fmaxf(s1, s2);
        if (smax > mq + DEFER_THR) {              // first valid edge: -inf -> taken
            float sc = __expf(mq - smax);         // first: exp(-inf)=0
            lq *= sc;
            f2 sc2 = {sc, sc};
#pragma unroll
            for (int j = 0; j < 8; ++j) acc2[j] *= sc2;
            mq = smax;
        }
        float pe1 = v1 ? __expf(s1 - mq) : 0.f;   // bounded by e^THR
        float pe2 = v2 ? __expf(s2 - mq) : 0.f;
        lq += pe1 + pe2;
        f2 pe1v = {pe1, pe1}, pe2v = {pe2, pe2};
#pragma unroll
        for (int j = 0; j < 4; ++j) {
            f2 w1 = {(float)fa1[j].x, (float)fa1[j].y};
            f2 w2 = {(float)fa2[j].x, (float)fa2[j].y};
            acc2[j] = __builtin_elementwise_fma(pe1v, w1,
                       __builtin_elementwise_fma(pe2v, w2, acc2[j]));
            f2 u1 = {(float)fb1[j].x, (float)fb1[j].y};
            f2 u2 = {(float)fb2[j].x, (float)fb2[j].y};
            acc2[4 + j] = __builtin_elementwise_fma(pe1v, u1,
                           __builtin_elementwise_fma(pe2v, u2, acc2[4 + j]));
        }
    };

    if (e0 < e1) {
        uint4 Aa1, Ab1, Aa2, Ab2, Ba1, Bb1, Ba2, Bb2;
        bool Av1, Av2, Bv1, Bv2;
        int base = e0;
        LOAD8(Aa1, Ab1, Aa2, Ab2, Av1, Av2, base);
        while (true) {
            int nxt = base + 8;
            bool more = nxt < e1;
            if (more) LOAD8(Ba1, Bb1, Ba2, Bb2, Bv1, Bv2, nxt);
            COMP8(Aa1, Ab1, Aa2, Ab2, Av1, Av2);
            if (!more) break;
            base = nxt;
            nxt = base + 8;
            more = nxt < e1;
            if (more) LOAD8(Aa1, Ab1, Aa2, Ab2, Av1, Av2, nxt);
            COMP8(Ba1, Bb1, Ba2, Bb2, Bv1, Bv2);
            if (!more) break;
            base = nxt;
        }
    }

    // ---- merge quarter states (4 shuffles total) ----
    float mstar = fmaxf(mq, __shfl_xor(mq, 16, 64));
    mstar = fmaxf(mstar, __shfl_xor(mstar, 32, 64));
    float sc = (lq > 0.f) ? __expf(mq - mstar) : 0.f;
    float lt = lq * sc;
    lt += __shfl_xor(lt, 16, 64);
    lt += __shfl_xor(lt, 32, 64);
    float inv = (lt > 0.f) ? 1.f / lt : 0.f;

    // ---- LDS transpose epilogue ----
    {
        float* wp = &xb[wv][(unsigned)lane * 20];
        f2 sc2 = {sc, sc};
#pragma unroll
        for (int k = 0; k < 4; ++k) {
            f2 lo = acc2[2 * k] * sc2;
            f2 hi = acc2[2 * k + 1] * sc2;
            *(float4*)(wp + 4 * k) = make_float4(lo.x, lo.y, hi.x, hi.y);
        }
    }
    asm volatile("s_waitcnt lgkmcnt(0)" ::: "memory");
    // lane L -> output dim d=L: col=d>>4, jp=d&15;
    // sum over q of V[q][col+4h][jp], then max over heads h
    {
        int col = lane >> 4, jp = lane & 15;
        float A[4];
#pragma unroll
        for (int h = 0; h < 4; ++h) {
            int rowb = (col + 4 * h) * 20 + jp;
            float v0 = xb[wv][rowb];
            float v1 = xb[wv][rowb + 16 * 20];
            float v2 = xb[wv][rowb + 32 * 20];
            float v3 = xb[wv][rowb + 48 * 20];
            A[h] = (v0 + v1) + (v2 + v3);
        }
        float r = fmaxf(fmaxf(A[0], A[1]), fmaxf(A[2], A[3])) * inv;
        out[(size_t)wid * DIM + lane] = r;
    }
}

extern "C" void kernel_launch(void* const* d_in, const int* in_sizes, int n_in,
                              void* d_out, int out_size, void* d_ws, size_t ws_size,
                              hipStream_t stream)
{
    const float* h_v  = (const float*)d_in[0];
    const int*   src  = (const int*)d_in[1];
    const int*   dst  = (const int*)d_in[2];
    const float* W_fc = (const float*)d_in[3];
    const float* b_fc = (const float*)d_in[4];
    const float* W_pi = (const float*)d_in[5];
    float* out = (float*)d_out;

    int N = in_sizes[0] / DIM;
    int E = in_sizes[1];

    // workspace layout
    _Float16* ft = (_Float16*)d_ws;                        // N*256*2 = 25.6 MB
    size_t ftB = (((size_t)N * FDIM * 2) + 255) & ~(size_t)255;
    char*  p    = (char*)d_ws + ftB;
    int*   cnt  = (int*)(p);                               // N
    int*   off  = (int*)(p + 256 * 1024);                  // N+1
    int*   cur  = (int*)(p + 512 * 1024);                  // N
    int*   bsum = (int*)(p + 768 * 1024);                  // ceil(N/256)
    int*   ssrc = (int*)(p + 1024 * 1024);                 // E

    int nb = (N + 255) / 256;
    int eb = (E + 255) / 256;            // exact-cover grid: 1 edge per thread
    fc_kernel<<<1024, 256, 0, stream>>>(h_v, W_fc, b_fc, ft, N);
    zero_kernel<<<256, 256, 0, stream>>>(cnt, N);
    hist_kernel<<<eb, 256, 0, stream>>>(dst, cnt, E);
    scanA_kernel<<<nb, 256, 0, stream>>>(cnt, off, bsum, N);
    scanB_kernel<<<1, 256, 0, stream>>>(bsum, nb);
    scanC_kernel<<<nb, 256, 0, stream>>>(off, cur, bsum, N, E);
    scatter_kernel<<<eb, 256, 0, stream>>>(src, dst, cur, ssrc, E);
    int blocks = (N * 64 + 255) / 256;   // one 64-lane wave per node
    agg_kernel<<<blocks, 256, 0, stream>>>(ft, off, ssrc, W_pi, out, N);
}

// Round 12
// 159.676 us; speedup vs baseline: 1.6952x; 1.2395x over previous
//
#include <hip/hip_runtime.h>
#include <math.h>

#define DIM 64
#define FDIM 256   // DIM * H (H=4)
#define DEFER_THR 4.0f

typedef _Float16 h2 __attribute__((ext_vector_type(2)));
typedef float f2 __attribute__((ext_vector_type(2)));

// ---------------- Stage 1: ft = f16(h_v @ W_fc^T + b_fc)  -> [N, 256] ----------------
__global__ __launch_bounds__(256) void fc_kernel(const float* __restrict__ h,
                                                 const float* __restrict__ W,
                                                 const float* __restrict__ b,
                                                 _Float16* __restrict__ ft, int N)
{
    int t = threadIdx.x;              // output column 0..255
    float w[DIM];
#pragma unroll
    for (int j = 0; j < DIM / 4; ++j) {
        float4 v = *(const float4*)(W + (size_t)t * DIM + j * 4);
        w[4 * j + 0] = v.x; w[4 * j + 1] = v.y;
        w[4 * j + 2] = v.z; w[4 * j + 3] = v.w;
    }
    float bt = b[t];
    for (int r = blockIdx.x; r < N; r += gridDim.x) {
        const float4* h4 = (const float4*)(h + (size_t)r * DIM);
        float acc = bt;
#pragma unroll
        for (int j = 0; j < DIM / 4; ++j) {
            float4 hv = h4[j];       // uniform address across the wave
            acc = fmaf(hv.x, w[4 * j + 0], acc);
            acc = fmaf(hv.y, w[4 * j + 1], acc);
            acc = fmaf(hv.z, w[4 * j + 2], acc);
            acc = fmaf(hv.w, w[4 * j + 3], acc);
        }
        ft[(size_t)r * FDIM + t] = (_Float16)acc;
    }
}

// ---------------- Counting sort of edges by dst ----------------
// hist + per-edge rank in one pass: the atomic's return value IS the rank of edge i
// within its dst segment (any within-segment order is valid for the softmax sum).
__global__ void hist_rank_kernel(const int* __restrict__ dst, int* __restrict__ cnt,
                                 int* __restrict__ rank, int E)
{
    int i = blockIdx.x * blockDim.x + threadIdx.x;
    if (i < E) rank[i] = atomicAdd(&cnt[dst[i]], 1);
}

__global__ __launch_bounds__(256) void scanA_kernel(const int* __restrict__ cnt,
                                                    int* __restrict__ off,
                                                    int* __restrict__ bsum, int N)
{
    __shared__ int sh[256];
    int t = threadIdx.x;
    int i = blockIdx.x * 256 + t;
    int v = (i < N) ? cnt[i] : 0;
    sh[t] = v;
    __syncthreads();
#pragma unroll
    for (int o = 1; o < 256; o <<= 1) {
        int x = (t >= o) ? sh[t - o] : 0;
        __syncthreads();
        sh[t] += x;
        __syncthreads();
    }
    if (i < N) off[i] = sh[t] - v;          // local exclusive
    if (t == 255) bsum[blockIdx.x] = sh[255];
}

__global__ __launch_bounds__(256) void scanB_kernel(int* __restrict__ bsum, int nb)
{
    __shared__ int sh[256];
    int t = threadIdx.x;
    int carry = 0;
    for (int base = 0; base < nb; base += 256) {
        int i = base + t;
        int v = (i < nb) ? bsum[i] : 0;
        sh[t] = v;
        __syncthreads();
#pragma unroll
        for (int o = 1; o < 256; o <<= 1) {
            int x = (t >= o) ? sh[t - o] : 0;
            __syncthreads();
            sh[t] += x;
            __syncthreads();
        }
        if (i < nb) bsum[i] = carry + sh[t] - v;   // exclusive
        int tot = sh[255];
        __syncthreads();
        carry += tot;
    }
}

__global__ void scanC_kernel(int* __restrict__ off, const int* __restrict__ bsum,
                             int N, int E)
{
    int i = blockIdx.x * blockDim.x + threadIdx.x;
    if (i < N) off[i] += bsum[i >> 8];
    if (i == 0) off[N] = E;
}

// Atomic-free scatter: pos = off[dst] + rank.  Coalesced reads, scattered 4B store.
__global__ void scatter_kernel(const int* __restrict__ src, const int* __restrict__ dst,
                               const int* __restrict__ off, const int* __restrict__ rank,
                               int* __restrict__ ssrc, int E)
{
    int i = blockIdx.x * blockDim.x + threadIdx.x;
    if (i < E) {
        int d = dst[i];
        ssrc[off[d] + rank[i]] = src[i];
    }
}

// ---------------- Fused: score + edge-softmax + weighted sum + head-max ----------------
// One wave per node. 8 edges/iter: quarter q owns edges base+q and base+q+4, each quarter
// keeps an independent online softmax (mq,lq,acc); 1 pack prefetched ahead.
// Epilogue: LDS transpose (padded) -> sum over quarters + max over heads -> coalesced store.
__global__ __launch_bounds__(256) void agg_kernel(const _Float16* __restrict__ ft,
                                                  const int* __restrict__ off,
                                                  const int* __restrict__ ssrc,
                                                  const float* __restrict__ Wpi,
                                                  float* __restrict__ out, int N)
{
    __shared__ float xb[4][1280];     // per-wave 64 lanes * 20 words (padded 16->20)
    int wid = (blockIdx.x * blockDim.x + threadIdx.x) >> 6;
    int wv  = threadIdx.x >> 6;       // wave within block
    int lane = threadIdx.x & 63;
    if (wid >= N) return;
    int q  = lane >> 4;
    int ql = lane & 15;

    // fdwh[k] = f16( ft[wid][16*ql+2k..2k+1] * Wpi[...] )
    h2 fdwh[8];
    {
        const float* wp = Wpi + ql * 16;
        const _Float16* drow = ft + (size_t)wid * FDIM + ql * 16;
        uint4 a = *(const uint4*)(drow);
        uint4 b = *(const uint4*)(drow + 8);
        const h2* da = (const h2*)&a;
        const h2* db = (const h2*)&b;
#pragma unroll
        for (int j = 0; j < 4; ++j) {
            h2 v = da[j], u = db[j];
            fdwh[j].x     = (_Float16)((float)v.x * wp[2 * j + 0]);
            fdwh[j].y     = (_Float16)((float)v.y * wp[2 * j + 1]);
            fdwh[4 + j].x = (_Float16)((float)u.x * wp[8 + 2 * j + 0]);
            fdwh[4 + j].y = (_Float16)((float)u.y * wp[8 + 2 * j + 1]);
        }
    }

    int e0 = off[wid], e1 = off[wid + 1];
    float mq = -INFINITY, lq = 0.f;
    f2 acc2[8];
#pragma unroll
    for (int j = 0; j < 8; ++j) acc2[j] = (f2){0.f, 0.f};

    auto LOAD8 = [&](uint4& a1, uint4& b1, uint4& a2, uint4& b2,
                     bool& v1, bool& v2, int bse) {
        int lo = bse + q, hi = bse + q + 4;
        v1 = lo < e1; v2 = hi < e1;
        int s1 = ssrc[v1 ? lo : e0];
        int s2 = ssrc[v2 ? hi : e0];
        const _Float16* r1 = ft + (size_t)s1 * FDIM + ql * 16;
        const _Float16* r2 = ft + (size_t)s2 * FDIM + ql * 16;
        a1 = *(const uint4*)(r1);
        b1 = *(const uint4*)(r1 + 8);
        a2 = *(const uint4*)(r2);
        b2 = *(const uint4*)(r2 + 8);
    };
    auto COMP8 = [&](uint4 a1, uint4 b1, uint4 a2, uint4 b2, bool v1, bool v2) {
        const h2* fa1 = (const h2*)&a1; const h2* fb1 = (const h2*)&b1;
        const h2* fa2 = (const h2*)&a2; const h2* fb2 = (const h2*)&b2;
        float p1 = 0.f, p2 = 0.f;
#pragma unroll
        for (int j = 0; j < 4; ++j) {
            p1 = __builtin_amdgcn_fdot2(fa1[j], fdwh[j], p1, false);
            p2 = __builtin_amdgcn_fdot2(fa2[j], fdwh[j], p2, false);
        }
#pragma unroll
        for (int j = 0; j < 4; ++j) {
            p1 = __builtin_amdgcn_fdot2(fb1[j], fdwh[4 + j], p1, false);
            p2 = __builtin_amdgcn_fdot2(fb2[j], fdwh[4 + j], p2, false);
        }
        p1 += __shfl_xor(p1, 1, 64);  p2 += __shfl_xor(p2, 1, 64);
        p1 += __shfl_xor(p1, 2, 64);  p2 += __shfl_xor(p2, 2, 64);
        p1 += __shfl_xor(p1, 4, 64);  p2 += __shfl_xor(p2, 4, 64);
        p1 += __shfl_xor(p1, 8, 64);  p2 += __shfl_xor(p2, 8, 64);
        float s1 = p1 > 0.f ? p1 : 0.2f * p1;     // LeakyReLU(0.2)
        float s2 = p2 > 0.f ? p2 : 0.2f * p2;
        if (!v1) s1 = -INFINITY;
        if (!v2) s2 = -INFINITY;
        float smax = fmaxf(s1, s2);
        if (smax > mq + DEFER_THR) {              // first valid edge: -inf -> taken
            float sc = __expf(mq - smax);         // first: exp(-inf)=0
            lq *= sc;
            f2 sc2 = {sc, sc};
#pragma unroll
            for (int j = 0; j < 8; ++j) acc2[j] *= sc2;
            mq = smax;
        }
        float pe1 = v1 ? __expf(s1 - mq) : 0.f;   // bounded by e^THR
        float pe2 = v2 ? __expf(s2 - mq) : 0.f;
        lq += pe1 + pe2;
        f2 pe1v = {pe1, pe1}, pe2v = {pe2, pe2};
#pragma unroll
        for (int j = 0; j < 4; ++j) {
            f2 w1 = {(float)fa1[j].x, (float)fa1[j].y};
            f2 w2 = {(float)fa2[j].x, (float)fa2[j].y};
            acc2[j] = __builtin_elementwise_fma(pe1v, w1,
                       __builtin_elementwise_fma(pe2v, w2, acc2[j]));
            f2 u1 = {(float)fb1[j].x, (float)fb1[j].y};
            f2 u2 = {(float)fb2[j].x, (float)fb2[j].y};
            acc2[4 + j] = __builtin_elementwise_fma(pe1v, u1,
                           __builtin_elementwise_fma(pe2v, u2, acc2[4 + j]));
        }
    };

    if (e0 < e1) {
        uint4 Aa1, Ab1, Aa2, Ab2, Ba1, Bb1, Ba2, Bb2;
        bool Av1, Av2, Bv1, Bv2;
        int base = e0;
        LOAD8(Aa1, Ab1, Aa2, Ab2, Av1, Av2, base);
        while (true) {
            int nxt = base + 8;
            bool more = nxt < e1;
            if (more) LOAD8(Ba1, Bb1, Ba2, Bb2, Bv1, Bv2, nxt);
            COMP8(Aa1, Ab1, Aa2, Ab2, Av1, Av2);
            if (!more) break;
            base = nxt;
            nxt = base + 8;
            more = nxt < e1;
            if (more) LOAD8(Aa1, Ab1, Aa2, Ab2, Av1, Av2, nxt);
            COMP8(Ba1, Bb1, Ba2, Bb2, Bv1, Bv2);
            if (!more) break;
            base = nxt;
        }
    }

    // ---- merge quarter states (4 shuffles total) ----
    float mstar = fmaxf(mq, __shfl_xor(mq, 16, 64));
    mstar = fmaxf(mstar, __shfl_xor(mstar, 32, 64));
    float sc = (lq > 0.f) ? __expf(mq - mstar) : 0.f;
    float lt = lq * sc;
    lt += __shfl_xor(lt, 16, 64);
    lt += __shfl_xor(lt, 32, 64);
    float inv = (lt > 0.f) ? 1.f / lt : 0.f;

    // ---- LDS transpose epilogue ----
    {
        float* wp = &xb[wv][(unsigned)lane * 20];
        f2 sc2 = {sc, sc};
#pragma unroll
        for (int k = 0; k < 4; ++k) {
            f2 lo = acc2[2 * k] * sc2;
            f2 hi = acc2[2 * k + 1] * sc2;
            *(float4*)(wp + 4 * k) = make_float4(lo.x, lo.y, hi.x, hi.y);
        }
    }
    asm volatile("s_waitcnt lgkmcnt(0)" ::: "memory");
    // lane L -> output dim d=L: col=d>>4, jp=d&15;
    // sum over q of V[q][col+4h][jp], then max over heads h
    {
        int col = lane >> 4, jp = lane & 15;
        float A[4];
#pragma unroll
        for (int h = 0; h < 4; ++h) {
            int rowb = (col + 4 * h) * 20 + jp;
            float v0 = xb[wv][rowb];
            float v1 = xb[wv][rowb + 16 * 20];
            float v2 = xb[wv][rowb + 32 * 20];
            float v3 = xb[wv][rowb + 48 * 20];
            A[h] = (v0 + v1) + (v2 + v3);
        }
        float r = fmaxf(fmaxf(A[0], A[1]), fmaxf(A[2], A[3])) * inv;
        out[(size_t)wid * DIM + lane] = r;
    }
}

extern "C" void kernel_launch(void* const* d_in, const int* in_sizes, int n_in,
                              void* d_out, int out_size, void* d_ws, size_t ws_size,
                              hipStream_t stream)
{
    const float* h_v  = (const float*)d_in[0];
    const int*   src  = (const int*)d_in[1];
    const int*   dst  = (const int*)d_in[2];
    const float* W_fc = (const float*)d_in[3];
    const float* b_fc = (const float*)d_in[4];
    const float* W_pi = (const float*)d_in[5];
    float* out = (float*)d_out;

    int N = in_sizes[0] / DIM;
    int E = in_sizes[1];

    // workspace layout
    _Float16* ft = (_Float16*)d_ws;                        // N*256*2 = 25.6 MB
    size_t ftB = (((size_t)N * FDIM * 2) + 255) & ~(size_t)255;
    char*  p    = (char*)d_ws + ftB;
    int*   cnt  = (int*)(p);                               // N          (@0)
    int*   off  = (int*)(p + 256 * 1024);                  // N+1        (@256KB)
    int*   bsum = (int*)(p + 512 * 1024);                  // ceil(N/256)(@512KB)
    int*   rank = (int*)(p + 768 * 1024);                  // E          (@768KB)
    int*   ssrc = (int*)(p + 768 * 1024 + ((size_t)E * 4 + 255 & ~(size_t)255)); // E

    int nb = (N + 255) / 256;
    int eb = (E + 255) / 256;            // 1 edge per thread
    fc_kernel<<<1024, 256, 0, stream>>>(h_v, W_fc, b_fc, ft, N);
    hipMemsetAsync(cnt, 0, (size_t)N * sizeof(int), stream);
    hist_rank_kernel<<<eb, 256, 0, stream>>>(dst, cnt, rank, E);
    scanA_kernel<<<nb, 256, 0, stream>>>(cnt, off, bsum, N);
    scanB_kernel<<<1, 256, 0, stream>>>(bsum, nb);
    scanC_kernel<<<nb, 256, 0, stream>>>(off, bsum, N, E);
    scatter_kernel<<<eb, 256, 0, stream>>>(src, dst, off, rank, ssrc, E);
    int blocks = (N * 64 + 255) / 256;   // one 64-lane wave per node
    agg_kernel<<<blocks, 256, 0, stream>>>(ft, off, ssrc, W_pi, out, N);
}